// Round 1
// baseline (7197.932 us; speedup 1.0000x reference)
//
#include <hip/hip_runtime.h>
#include <math.h>

// VisionMamba forward, fp32 baseline.
// B=64, L=196 (14x14 patches), D_MODEL=192, D_INNER=384, D_STATE=16, DT_RANK=12, DEPTH=24.
// Workspace layout (floats):
//   residual 0..2408448, hidden, normed, xz(12544x768), xc(12544x384), y(12544x384),
//   x_dbl(12544x44), pooled(64x192).  Total ~108.2 MB.

#define DEPTH 24
#define DM 192
#define DI 384
#define DS 16
#define DR 12
#define SEQL 196
#define BATCH 64
#define MROWS (BATCH*SEQL)   // 12544

__device__ __forceinline__ float sigmoidf_(float x) { return 1.f / (1.f + __expf(-x)); }

// ---------------- residual += hidden; out = LayerNorm(residual) ----------------
// block = 256 (4 waves), one wave per row of 192.
__global__ void ln_kernel(float* __restrict__ residual, const float* __restrict__ hidden,
                          const float* __restrict__ w, const float* __restrict__ b,
                          float* __restrict__ out) {
    int wave = threadIdx.x >> 6, lane = threadIdx.x & 63;
    int row = blockIdx.x * 4 + wave;
    float* rr = residual + (size_t)row * DM;
    const float* hr = hidden + (size_t)row * DM;
    float v0 = rr[lane]       + hr[lane];
    float v1 = rr[lane + 64]  + hr[lane + 64];
    float v2 = rr[lane + 128] + hr[lane + 128];
    rr[lane] = v0; rr[lane + 64] = v1; rr[lane + 128] = v2;
    float s = v0 + v1 + v2;
    #pragma unroll
    for (int off = 32; off > 0; off >>= 1) s += __shfl_down(s, off);
    float mean = __shfl(s, 0) * (1.f / DM);
    float d0 = v0 - mean, d1 = v1 - mean, d2 = v2 - mean;
    float q = d0 * d0 + d1 * d1 + d2 * d2;
    #pragma unroll
    for (int off = 32; off > 0; off >>= 1) q += __shfl_down(q, off);
    float rstd = rsqrtf(__shfl(q, 0) * (1.f / DM) + 1e-5f);
    float* orow = out + (size_t)row * DM;
    orow[lane]       = d0 * rstd * w[lane]       + b[lane];
    orow[lane + 64]  = d1 * rstd * w[lane + 64]  + b[lane + 64];
    orow[lane + 128] = d2 * rstd * w[lane + 128] + b[lane + 128];
}

// ---------------- Tiled GEMM: C[M,N] = A[M,K] * W[N,K]^T (+bias) ----------------
// BM=BN=128, BK=16, block 256 threads, 8x8 micro-tile. M must be divisible by 128.
template<bool BIAS>
__global__ __launch_bounds__(256, 2) void gemm128(const float* __restrict__ A,
        const float* __restrict__ W, const float* __restrict__ bias,
        float* __restrict__ C, int N, int K) {
    __shared__ float As[16][132];
    __shared__ float Ws[16][132];
    int t = threadIdx.x;
    int m0 = blockIdx.x * 128, n0 = blockIdx.y * 128;
    int lr = t >> 1, lk = (t & 1) * 4;
    const float* Ap = A + (size_t)(m0 + lr) * K + lk;
    int wn = n0 + lr;
    bool wv = wn < N;
    const float* Wp = W + (size_t)(wv ? wn : 0) * K + lk;
    int tm = (t >> 4) * 8, tn = (t & 15) * 8;
    float acc[8][8];
    #pragma unroll
    for (int i = 0; i < 8; i++)
        #pragma unroll
        for (int j = 0; j < 8; j++) acc[i][j] = 0.f;

    for (int k0 = 0; k0 < K; k0 += 16) {
        float4 a0 = *(const float4*)(Ap + k0);
        float4 a1 = *(const float4*)(Ap + k0 + 8);
        float4 w0 = make_float4(0.f, 0.f, 0.f, 0.f), w1 = w0;
        if (wv) { w0 = *(const float4*)(Wp + k0); w1 = *(const float4*)(Wp + k0 + 8); }
        __syncthreads();
        As[lk + 0][lr] = a0.x; As[lk + 1][lr] = a0.y; As[lk + 2][lr] = a0.z; As[lk + 3][lr] = a0.w;
        As[lk + 8][lr] = a1.x; As[lk + 9][lr] = a1.y; As[lk + 10][lr] = a1.z; As[lk + 11][lr] = a1.w;
        Ws[lk + 0][lr] = w0.x; Ws[lk + 1][lr] = w0.y; Ws[lk + 2][lr] = w0.z; Ws[lk + 3][lr] = w0.w;
        Ws[lk + 8][lr] = w1.x; Ws[lk + 9][lr] = w1.y; Ws[lk + 10][lr] = w1.z; Ws[lk + 11][lr] = w1.w;
        __syncthreads();
        #pragma unroll
        for (int kk = 0; kk < 16; kk++) {
            float4 x0 = *(const float4*)&As[kk][tm];
            float4 x1 = *(const float4*)&As[kk][tm + 4];
            float4 y0 = *(const float4*)&Ws[kk][tn];
            float4 y1 = *(const float4*)&Ws[kk][tn + 4];
            float av[8] = {x0.x, x0.y, x0.z, x0.w, x1.x, x1.y, x1.z, x1.w};
            float bv[8] = {y0.x, y0.y, y0.z, y0.w, y1.x, y1.y, y1.z, y1.w};
            #pragma unroll
            for (int i = 0; i < 8; i++)
                #pragma unroll
                for (int j = 0; j < 8; j++) acc[i][j] = fmaf(av[i], bv[j], acc[i][j]);
        }
    }
    #pragma unroll
    for (int i = 0; i < 8; i++) {
        float* cr = C + (size_t)(m0 + tm + i) * N;
        #pragma unroll
        for (int jv = 0; jv < 8; jv += 4) {
            int n = n0 + tn + jv;
            if (n < N) {
                float4 v = {acc[i][jv], acc[i][jv + 1], acc[i][jv + 2], acc[i][jv + 3]};
                if (BIAS) { v.x += bias[n]; v.y += bias[n + 1]; v.z += bias[n + 2]; v.w += bias[n + 3]; }
                *(float4*)(cr + n) = v;
            }
        }
    }
}

// ---------------- Patch-embed GEMM with im2col A-loader ----------------
// C[12544,192] = im2col(x)[12544,768] * patch_w[192,768]^T + patch_b
__global__ __launch_bounds__(256, 2) void gemm_patch(const float* __restrict__ X,
        const float* __restrict__ W, const float* __restrict__ bias, float* __restrict__ C) {
    const int N = 192, K = 768;
    __shared__ float As[16][132];
    __shared__ float Ws[16][132];
    int t = threadIdx.x;
    int m0 = blockIdx.x * 128, n0 = blockIdx.y * 128;
    int lr = t >> 1, lk = (t & 1) * 4;
    int m = m0 + lr;
    int b = m / 196, r = m % 196, py = r / 14, px = r % 14;
    const float* xb = X + (size_t)b * 150528 + py * 3584 + px * 16;  // b*3*224*224 + (16py)*224 + 16px
    int wn = n0 + lr;
    bool wv = wn < N;
    const float* Wp = W + (size_t)(wv ? wn : 0) * K + lk;
    int tm = (t >> 4) * 8, tn = (t & 15) * 8;
    float acc[8][8];
    #pragma unroll
    for (int i = 0; i < 8; i++)
        #pragma unroll
        for (int j = 0; j < 8; j++) acc[i][j] = 0.f;

    for (int k0 = 0; k0 < K; k0 += 16) {
        int k = k0 + lk;
        int ci = k >> 8, ky = (k >> 4) & 15;  // kx = k & 15 == lk
        const float* p = xb + ci * 50176 + ky * 224 + (k & 15);
        float4 a0 = *(const float4*)p;
        float4 a1 = *(const float4*)(p + 8);
        float4 w0 = make_float4(0.f, 0.f, 0.f, 0.f), w1 = w0;
        if (wv) { w0 = *(const float4*)(Wp + k0); w1 = *(const float4*)(Wp + k0 + 8); }
        __syncthreads();
        As[lk + 0][lr] = a0.x; As[lk + 1][lr] = a0.y; As[lk + 2][lr] = a0.z; As[lk + 3][lr] = a0.w;
        As[lk + 8][lr] = a1.x; As[lk + 9][lr] = a1.y; As[lk + 10][lr] = a1.z; As[lk + 11][lr] = a1.w;
        Ws[lk + 0][lr] = w0.x; Ws[lk + 1][lr] = w0.y; Ws[lk + 2][lr] = w0.z; Ws[lk + 3][lr] = w0.w;
        Ws[lk + 8][lr] = w1.x; Ws[lk + 9][lr] = w1.y; Ws[lk + 10][lr] = w1.z; Ws[lk + 11][lr] = w1.w;
        __syncthreads();
        #pragma unroll
        for (int kk = 0; kk < 16; kk++) {
            float4 x0 = *(const float4*)&As[kk][tm];
            float4 x1 = *(const float4*)&As[kk][tm + 4];
            float4 y0 = *(const float4*)&Ws[kk][tn];
            float4 y1 = *(const float4*)&Ws[kk][tn + 4];
            float av[8] = {x0.x, x0.y, x0.z, x0.w, x1.x, x1.y, x1.z, x1.w};
            float bv[8] = {y0.x, y0.y, y0.z, y0.w, y1.x, y1.y, y1.z, y1.w};
            #pragma unroll
            for (int i = 0; i < 8; i++)
                #pragma unroll
                for (int j = 0; j < 8; j++) acc[i][j] = fmaf(av[i], bv[j], acc[i][j]);
        }
    }
    #pragma unroll
    for (int i = 0; i < 8; i++) {
        float* cr = C + (size_t)(m0 + tm + i) * N;
        #pragma unroll
        for (int jv = 0; jv < 8; jv += 4) {
            int n = n0 + tn + jv;
            if (n < N) {
                float4 v = {acc[i][jv] + bias[n], acc[i][jv + 1] + bias[n + 1],
                            acc[i][jv + 2] + bias[n + 2], acc[i][jv + 3] + bias[n + 3]};
                *(float4*)(cr + n) = v;
            }
        }
    }
}

// ---------------- Small GEMM: BM=BN=64, BK=32, 4x4 micro-tile (x_proj, head) ----------------
template<bool BIAS>
__global__ __launch_bounds__(256, 2) void gemm64(const float* __restrict__ A,
        const float* __restrict__ W, const float* __restrict__ bias,
        float* __restrict__ C, int M, int N, int K) {
    __shared__ float As[32][68];
    __shared__ float Ws[32][68];
    int t = threadIdx.x;
    int m0 = blockIdx.x * 64, n0 = blockIdx.y * 64;
    int lr = t >> 2, lk = (t & 3) * 4;
    int am = m0 + lr; bool avld = am < M;
    const float* Ap = A + (size_t)(avld ? am : 0) * K + lk;
    int wn = n0 + lr; bool wv = wn < N;
    const float* Wp = W + (size_t)(wv ? wn : 0) * K + lk;
    int tm = (t >> 4) * 4, tn = (t & 15) * 4;
    float acc[4][4];
    #pragma unroll
    for (int i = 0; i < 4; i++)
        #pragma unroll
        for (int j = 0; j < 4; j++) acc[i][j] = 0.f;

    for (int k0 = 0; k0 < K; k0 += 32) {
        float4 a0 = make_float4(0.f, 0.f, 0.f, 0.f), a1 = a0, w0 = a0, w1 = a0;
        if (avld) { a0 = *(const float4*)(Ap + k0); a1 = *(const float4*)(Ap + k0 + 16); }
        if (wv)   { w0 = *(const float4*)(Wp + k0); w1 = *(const float4*)(Wp + k0 + 16); }
        __syncthreads();
        As[lk + 0][lr] = a0.x; As[lk + 1][lr] = a0.y; As[lk + 2][lr] = a0.z; As[lk + 3][lr] = a0.w;
        As[lk + 16][lr] = a1.x; As[lk + 17][lr] = a1.y; As[lk + 18][lr] = a1.z; As[lk + 19][lr] = a1.w;
        Ws[lk + 0][lr] = w0.x; Ws[lk + 1][lr] = w0.y; Ws[lk + 2][lr] = w0.z; Ws[lk + 3][lr] = w0.w;
        Ws[lk + 16][lr] = w1.x; Ws[lk + 17][lr] = w1.y; Ws[lk + 18][lr] = w1.z; Ws[lk + 19][lr] = w1.w;
        __syncthreads();
        #pragma unroll
        for (int kk = 0; kk < 32; kk++) {
            float4 x0 = *(const float4*)&As[kk][tm];
            float4 y0 = *(const float4*)&Ws[kk][tn];
            float av[4] = {x0.x, x0.y, x0.z, x0.w};
            float bv[4] = {y0.x, y0.y, y0.z, y0.w};
            #pragma unroll
            for (int i = 0; i < 4; i++)
                #pragma unroll
                for (int j = 0; j < 4; j++) acc[i][j] = fmaf(av[i], bv[j], acc[i][j]);
        }
    }
    #pragma unroll
    for (int i = 0; i < 4; i++) {
        int m = m0 + tm + i;
        if (m >= M) continue;
        float* cr = C + (size_t)m * N;
        int n = n0 + tn;
        if (n < N) {
            float4 v = {acc[i][0], acc[i][1], acc[i][2], acc[i][3]};
            if (BIAS) { v.x += bias[n]; v.y += bias[n + 1]; v.z += bias[n + 2]; v.w += bias[n + 3]; }
            *(float4*)(cr + n) = v;
        }
    }
}

// ---------------- depthwise causal conv(4) + SiLU: xz[:, :384] -> xc ----------------
__global__ void conv_silu_kernel(const float* __restrict__ xz, const float* __restrict__ cw,
                                 const float* __restrict__ cb, float* __restrict__ xc) {
    int idx = blockIdx.x * 256 + threadIdx.x;
    if (idx >= MROWS * DI) return;
    int e = idx % DI; int bl = idx / DI; int l = bl % SEQL; int b = bl / SEQL;
    const float* base = xz + (size_t)(b * SEQL) * 768 + e;
    float w0 = cw[e * 4], w1 = cw[e * 4 + 1], w2 = cw[e * 4 + 2], w3 = cw[e * 4 + 3];
    float acc = cb[e];
    if (l >= 3) acc = fmaf(base[(size_t)(l - 3) * 768], w0, acc);
    if (l >= 2) acc = fmaf(base[(size_t)(l - 2) * 768], w1, acc);
    if (l >= 1) acc = fmaf(base[(size_t)(l - 1) * 768], w2, acc);
    acc = fmaf(base[(size_t)l * 768], w3, acc);
    xc[idx] = acc * sigmoidf_(acc);
}

// ---------------- fused selective scan ----------------
// grid (64, 3), block 128: one (batch, e-chunk) per block. Fuses delta = softplus(dt@dtw^T + dtb),
// the h-recurrence, y = h.C + xc*D, and the silu(z) gate. x_dbl rows for this b staged in LDS once.
__global__ void scan_kernel(const float* __restrict__ xdbl, const float* __restrict__ xc,
        const float* __restrict__ xz, const float* __restrict__ dtw, const float* __restrict__ dtb,
        const float* __restrict__ a_log, const float* __restrict__ Dp, float* __restrict__ y) {
    __shared__ float sd[SEQL * 44];
    int b = blockIdx.x;
    int e = blockIdx.y * 128 + threadIdx.x;
    const float* src = xdbl + (size_t)b * SEQL * 44;
    for (int i = threadIdx.x; i < SEQL * 44; i += 128) sd[i] = src[i];
    __syncthreads();
    float Av[DS];
    #pragma unroll
    for (int n = 0; n < DS; n++) Av[n] = -__expf(a_log[(size_t)e * DS + n]);
    float wdt[DR];
    #pragma unroll
    for (int j = 0; j < DR; j++) wdt[j] = dtw[(size_t)e * DR + j];
    float db = dtb[e], Dv = Dp[e];
    float h[DS];
    #pragma unroll
    for (int n = 0; n < DS; n++) h[n] = 0.f;
    const float* xcp = xc + (size_t)b * SEQL * DI + e;
    const float* zp  = xz + (size_t)b * SEQL * 768 + DI + e;
    float* yp = y + (size_t)b * SEQL * DI + e;
    for (int l = 0; l < SEQL; l++) {
        float xcv = xcp[(size_t)l * DI];
        float zv  = zp[(size_t)l * 768];
        const float* row = &sd[l * 44];
        float d = db;
        #pragma unroll
        for (int j = 0; j < DR; j++) d = fmaf(row[j], wdt[j], d);
        d = (d > 20.f) ? d : log1pf(__expf(d));  // softplus
        float du = d * xcv;
        float acc = 0.f;
        #pragma unroll
        for (int n = 0; n < DS; n++) {
            float dA = __expf(d * Av[n]);
            h[n] = fmaf(h[n], dA, du * row[12 + n]);
            acc = fmaf(h[n], row[28 + n], acc);
        }
        float yv = fmaf(xcv, Dv, acc);
        yp[(size_t)l * DI] = yv * zv * sigmoidf_(zv);
    }
}

// ---------------- mean over L ----------------
__global__ void pool_kernel(const float* __restrict__ normed, float* __restrict__ pooled) {
    int b = blockIdx.x, d = threadIdx.x;
    float s = 0.f;
    for (int l = 0; l < SEQL; l++) s += normed[(size_t)(b * SEQL + l) * DM + d];
    pooled[b * DM + d] = s * (1.f / 196.f);
}

extern "C" void kernel_launch(void* const* d_in, const int* in_sizes, int n_in,
                              void* d_out, int out_size, void* d_ws, size_t ws_size,
                              hipStream_t stream) {
    const float* x       = (const float*)d_in[0];
    const float* patch_w = (const float*)d_in[1];
    const float* patch_b = (const float*)d_in[2];
    const float* norm_w  = (const float*)d_in[3];
    const float* norm_b  = (const float*)d_in[4];
    const float* in_w    = (const float*)d_in[5];
    const float* conv_w  = (const float*)d_in[6];
    const float* conv_b  = (const float*)d_in[7];
    const float* xp_w    = (const float*)d_in[8];
    const float* dt_w    = (const float*)d_in[9];
    const float* dt_b    = (const float*)d_in[10];
    const float* A_log   = (const float*)d_in[11];
    const float* Dp      = (const float*)d_in[12];
    const float* out_w   = (const float*)d_in[13];
    const float* normf_w = (const float*)d_in[14];
    const float* normf_b = (const float*)d_in[15];
    const float* head_w  = (const float*)d_in[16];
    const float* head_b  = (const float*)d_in[17];

    float* ws = (float*)d_ws;
    float* residual = ws;                    // 12544*192
    float* hidden   = ws + 2408448;          // 12544*192
    float* normed   = ws + 4816896;          // 12544*192
    float* xz       = ws + 7225344;          // 12544*768
    float* xc       = ws + 16859136;         // 12544*384
    float* yb       = ws + 21676032;         // 12544*384
    float* xdbl     = ws + 26492928;         // 12544*44
    float* pooled   = ws + 27044864;         // 64*192

    hipMemsetAsync(residual, 0, (size_t)2408448 * sizeof(float), stream);

    gemm_patch<<<dim3(98, 2), 256, 0, stream>>>(x, patch_w, patch_b, hidden);

    for (int d = 0; d < DEPTH; ++d) {
        ln_kernel<<<3136, 256, 0, stream>>>(residual, hidden, norm_w + d * DM, norm_b + d * DM, normed);
        gemm128<false><<<dim3(98, 6), 256, 0, stream>>>(normed, in_w + (size_t)d * 768 * 192, nullptr,
                                                        xz, 768, 192);
        conv_silu_kernel<<<18816, 256, 0, stream>>>(xz, conv_w + d * DI * 4, conv_b + d * DI, xc);
        gemm64<false><<<dim3(196, 1), 256, 0, stream>>>(xc, xp_w + (size_t)d * 44 * 384, nullptr,
                                                        xdbl, MROWS, 44, 384);
        scan_kernel<<<dim3(64, 3), 128, 0, stream>>>(xdbl, xc, xz, dt_w + d * DI * DR, dt_b + d * DI,
                                                     A_log + d * DI * DS, Dp + d * DI, yb);
        gemm128<false><<<dim3(98, 2), 256, 0, stream>>>(yb, out_w + (size_t)d * 192 * 384, nullptr,
                                                        hidden, 192, 384);
    }

    ln_kernel<<<3136, 256, 0, stream>>>(residual, hidden, normf_w, normf_b, normed);
    pool_kernel<<<64, 192, 0, stream>>>(normed, pooled);
    gemm64<true><<<dim3(1, 16), 256, 0, stream>>>(pooled, head_w, head_b, (float*)d_out, 64, 1000, 192);
}

// Round 2
// 6236.136 us; speedup vs baseline: 1.1542x; 1.1542x over previous
//
#include <hip/hip_runtime.h>
#include <math.h>

// VisionMamba forward, fp32. Round 2: wave-parallel chunked selective scan.
// B=64, L=196, D_MODEL=192, D_INNER=384, D_STATE=16, DT_RANK=12, DEPTH=24.

#define DEPTH 24
#define DM 192
#define DI 384
#define DS 16
#define DR 12
#define SEQL 196
#define BATCH 64
#define MROWS (BATCH*SEQL)   // 12544

__device__ __forceinline__ float sigmoidf_(float x) { return 1.f / (1.f + __expf(-x)); }

// ---------------- residual += hidden; out = LayerNorm(residual) ----------------
__global__ void ln_kernel(float* __restrict__ residual, const float* __restrict__ hidden,
                          const float* __restrict__ w, const float* __restrict__ b,
                          float* __restrict__ out) {
    int wave = threadIdx.x >> 6, lane = threadIdx.x & 63;
    int row = blockIdx.x * 4 + wave;
    float* rr = residual + (size_t)row * DM;
    const float* hr = hidden + (size_t)row * DM;
    float v0 = rr[lane]       + hr[lane];
    float v1 = rr[lane + 64]  + hr[lane + 64];
    float v2 = rr[lane + 128] + hr[lane + 128];
    rr[lane] = v0; rr[lane + 64] = v1; rr[lane + 128] = v2;
    float s = v0 + v1 + v2;
    #pragma unroll
    for (int off = 32; off > 0; off >>= 1) s += __shfl_down(s, off);
    float mean = __shfl(s, 0) * (1.f / DM);
    float d0 = v0 - mean, d1 = v1 - mean, d2 = v2 - mean;
    float q = d0 * d0 + d1 * d1 + d2 * d2;
    #pragma unroll
    for (int off = 32; off > 0; off >>= 1) q += __shfl_down(q, off);
    float rstd = rsqrtf(__shfl(q, 0) * (1.f / DM) + 1e-5f);
    float* orow = out + (size_t)row * DM;
    orow[lane]       = d0 * rstd * w[lane]       + b[lane];
    orow[lane + 64]  = d1 * rstd * w[lane + 64]  + b[lane + 64];
    orow[lane + 128] = d2 * rstd * w[lane + 128] + b[lane + 128];
}

// ---------------- Tiled GEMM: C[M,N] = A[M,K] * W[N,K]^T (+bias) ----------------
template<bool BIAS>
__global__ __launch_bounds__(256, 2) void gemm128(const float* __restrict__ A,
        const float* __restrict__ W, const float* __restrict__ bias,
        float* __restrict__ C, int N, int K) {
    __shared__ float As[16][132];
    __shared__ float Ws[16][132];
    int t = threadIdx.x;
    int m0 = blockIdx.x * 128, n0 = blockIdx.y * 128;
    int lr = t >> 1, lk = (t & 1) * 4;
    const float* Ap = A + (size_t)(m0 + lr) * K + lk;
    int wn = n0 + lr;
    bool wv = wn < N;
    const float* Wp = W + (size_t)(wv ? wn : 0) * K + lk;
    int tm = (t >> 4) * 8, tn = (t & 15) * 8;
    float acc[8][8];
    #pragma unroll
    for (int i = 0; i < 8; i++)
        #pragma unroll
        for (int j = 0; j < 8; j++) acc[i][j] = 0.f;

    for (int k0 = 0; k0 < K; k0 += 16) {
        float4 a0 = *(const float4*)(Ap + k0);
        float4 a1 = *(const float4*)(Ap + k0 + 8);
        float4 w0 = make_float4(0.f, 0.f, 0.f, 0.f), w1 = w0;
        if (wv) { w0 = *(const float4*)(Wp + k0); w1 = *(const float4*)(Wp + k0 + 8); }
        __syncthreads();
        As[lk + 0][lr] = a0.x; As[lk + 1][lr] = a0.y; As[lk + 2][lr] = a0.z; As[lk + 3][lr] = a0.w;
        As[lk + 8][lr] = a1.x; As[lk + 9][lr] = a1.y; As[lk + 10][lr] = a1.z; As[lk + 11][lr] = a1.w;
        Ws[lk + 0][lr] = w0.x; Ws[lk + 1][lr] = w0.y; Ws[lk + 2][lr] = w0.z; Ws[lk + 3][lr] = w0.w;
        Ws[lk + 8][lr] = w1.x; Ws[lk + 9][lr] = w1.y; Ws[lk + 10][lr] = w1.z; Ws[lk + 11][lr] = w1.w;
        __syncthreads();
        #pragma unroll
        for (int kk = 0; kk < 16; kk++) {
            float4 x0 = *(const float4*)&As[kk][tm];
            float4 x1 = *(const float4*)&As[kk][tm + 4];
            float4 y0 = *(const float4*)&Ws[kk][tn];
            float4 y1 = *(const float4*)&Ws[kk][tn + 4];
            float av[8] = {x0.x, x0.y, x0.z, x0.w, x1.x, x1.y, x1.z, x1.w};
            float bv[8] = {y0.x, y0.y, y0.z, y0.w, y1.x, y1.y, y1.z, y1.w};
            #pragma unroll
            for (int i = 0; i < 8; i++)
                #pragma unroll
                for (int j = 0; j < 8; j++) acc[i][j] = fmaf(av[i], bv[j], acc[i][j]);
        }
    }
    #pragma unroll
    for (int i = 0; i < 8; i++) {
        float* cr = C + (size_t)(m0 + tm + i) * N;
        #pragma unroll
        for (int jv = 0; jv < 8; jv += 4) {
            int n = n0 + tn + jv;
            if (n < N) {
                float4 v = {acc[i][jv], acc[i][jv + 1], acc[i][jv + 2], acc[i][jv + 3]};
                if (BIAS) { v.x += bias[n]; v.y += bias[n + 1]; v.z += bias[n + 2]; v.w += bias[n + 3]; }
                *(float4*)(cr + n) = v;
            }
        }
    }
}

// ---------------- Patch-embed GEMM with im2col A-loader ----------------
__global__ __launch_bounds__(256, 2) void gemm_patch(const float* __restrict__ X,
        const float* __restrict__ W, const float* __restrict__ bias, float* __restrict__ C) {
    const int N = 192, K = 768;
    __shared__ float As[16][132];
    __shared__ float Ws[16][132];
    int t = threadIdx.x;
    int m0 = blockIdx.x * 128, n0 = blockIdx.y * 128;
    int lr = t >> 1, lk = (t & 1) * 4;
    int m = m0 + lr;
    int b = m / 196, r = m % 196, py = r / 14, px = r % 14;
    const float* xb = X + (size_t)b * 150528 + py * 3584 + px * 16;
    int wn = n0 + lr;
    bool wv = wn < N;
    const float* Wp = W + (size_t)(wv ? wn : 0) * K + lk;
    int tm = (t >> 4) * 8, tn = (t & 15) * 8;
    float acc[8][8];
    #pragma unroll
    for (int i = 0; i < 8; i++)
        #pragma unroll
        for (int j = 0; j < 8; j++) acc[i][j] = 0.f;

    for (int k0 = 0; k0 < 768; k0 += 16) {
        int k = k0 + lk;
        int ci = k >> 8, ky = (k >> 4) & 15;
        const float* p = xb + ci * 50176 + ky * 224 + (k & 15);
        float4 a0 = *(const float4*)p;
        float4 a1 = *(const float4*)(p + 8);
        float4 w0 = make_float4(0.f, 0.f, 0.f, 0.f), w1 = w0;
        if (wv) { w0 = *(const float4*)(Wp + k0); w1 = *(const float4*)(Wp + k0 + 8); }
        __syncthreads();
        As[lk + 0][lr] = a0.x; As[lk + 1][lr] = a0.y; As[lk + 2][lr] = a0.z; As[lk + 3][lr] = a0.w;
        As[lk + 8][lr] = a1.x; As[lk + 9][lr] = a1.y; As[lk + 10][lr] = a1.z; As[lk + 11][lr] = a1.w;
        Ws[lk + 0][lr] = w0.x; Ws[lk + 1][lr] = w0.y; Ws[lk + 2][lr] = w0.z; Ws[lk + 3][lr] = w0.w;
        Ws[lk + 8][lr] = w1.x; Ws[lk + 9][lr] = w1.y; Ws[lk + 10][lr] = w1.z; Ws[lk + 11][lr] = w1.w;
        __syncthreads();
        #pragma unroll
        for (int kk = 0; kk < 16; kk++) {
            float4 x0 = *(const float4*)&As[kk][tm];
            float4 x1 = *(const float4*)&As[kk][tm + 4];
            float4 y0 = *(const float4*)&Ws[kk][tn];
            float4 y1 = *(const float4*)&Ws[kk][tn + 4];
            float av[8] = {x0.x, x0.y, x0.z, x0.w, x1.x, x1.y, x1.z, x1.w};
            float bv[8] = {y0.x, y0.y, y0.z, y0.w, y1.x, y1.y, y1.z, y1.w};
            #pragma unroll
            for (int i = 0; i < 8; i++)
                #pragma unroll
                for (int j = 0; j < 8; j++) acc[i][j] = fmaf(av[i], bv[j], acc[i][j]);
        }
    }
    #pragma unroll
    for (int i = 0; i < 8; i++) {
        float* cr = C + (size_t)(m0 + tm + i) * N;
        #pragma unroll
        for (int jv = 0; jv < 8; jv += 4) {
            int n = n0 + tn + jv;
            if (n < N) {
                float4 v = {acc[i][jv] + bias[n], acc[i][jv + 1] + bias[n + 1],
                            acc[i][jv + 2] + bias[n + 2], acc[i][jv + 3] + bias[n + 3]};
                *(float4*)(cr + n) = v;
            }
        }
    }
}

// ---------------- Small GEMM: BM=BN=64, BK=32, 4x4 micro-tile ----------------
template<bool BIAS>
__global__ __launch_bounds__(256, 2) void gemm64(const float* __restrict__ A,
        const float* __restrict__ W, const float* __restrict__ bias,
        float* __restrict__ C, int M, int N, int K) {
    __shared__ float As[32][68];
    __shared__ float Ws[32][68];
    int t = threadIdx.x;
    int m0 = blockIdx.x * 64, n0 = blockIdx.y * 64;
    int lr = t >> 2, lk = (t & 3) * 4;
    int am = m0 + lr; bool avld = am < M;
    const float* Ap = A + (size_t)(avld ? am : 0) * K + lk;
    int wn = n0 + lr; bool wv = wn < N;
    const float* Wp = W + (size_t)(wv ? wn : 0) * K + lk;
    int tm = (t >> 4) * 4, tn = (t & 15) * 4;
    float acc[4][4];
    #pragma unroll
    for (int i = 0; i < 4; i++)
        #pragma unroll
        for (int j = 0; j < 4; j++) acc[i][j] = 0.f;

    for (int k0 = 0; k0 < K; k0 += 32) {
        float4 a0 = make_float4(0.f, 0.f, 0.f, 0.f), a1 = a0, w0 = a0, w1 = a0;
        if (avld) { a0 = *(const float4*)(Ap + k0); a1 = *(const float4*)(Ap + k0 + 16); }
        if (wv)   { w0 = *(const float4*)(Wp + k0); w1 = *(const float4*)(Wp + k0 + 16); }
        __syncthreads();
        As[lk + 0][lr] = a0.x; As[lk + 1][lr] = a0.y; As[lk + 2][lr] = a0.z; As[lk + 3][lr] = a0.w;
        As[lk + 16][lr] = a1.x; As[lk + 17][lr] = a1.y; As[lk + 18][lr] = a1.z; As[lk + 19][lr] = a1.w;
        Ws[lk + 0][lr] = w0.x; Ws[lk + 1][lr] = w0.y; Ws[lk + 2][lr] = w0.z; Ws[lk + 3][lr] = w0.w;
        Ws[lk + 16][lr] = w1.x; Ws[lk + 17][lr] = w1.y; Ws[lk + 18][lr] = w1.z; Ws[lk + 19][lr] = w1.w;
        __syncthreads();
        #pragma unroll
        for (int kk = 0; kk < 32; kk++) {
            float4 x0 = *(const float4*)&As[kk][tm];
            float4 y0 = *(const float4*)&Ws[kk][tn];
            float av[4] = {x0.x, x0.y, x0.z, x0.w};
            float bv[4] = {y0.x, y0.y, y0.z, y0.w};
            #pragma unroll
            for (int i = 0; i < 4; i++)
                #pragma unroll
                for (int j = 0; j < 4; j++) acc[i][j] = fmaf(av[i], bv[j], acc[i][j]);
        }
    }
    #pragma unroll
    for (int i = 0; i < 4; i++) {
        int m = m0 + tm + i;
        if (m >= M) continue;
        float* cr = C + (size_t)m * N;
        int n = n0 + tn;
        if (n < N) {
            float4 v = {acc[i][0], acc[i][1], acc[i][2], acc[i][3]};
            if (BIAS) { v.x += bias[n]; v.y += bias[n + 1]; v.z += bias[n + 2]; v.w += bias[n + 3]; }
            *(float4*)(cr + n) = v;
        }
    }
}

// ---------------- depthwise causal conv(4) + SiLU ----------------
__global__ void conv_silu_kernel(const float* __restrict__ xz, const float* __restrict__ cw,
                                 const float* __restrict__ cb, float* __restrict__ xc) {
    int idx = blockIdx.x * 256 + threadIdx.x;
    if (idx >= MROWS * DI) return;
    int e = idx % DI; int bl = idx / DI; int l = bl % SEQL; int b = bl / SEQL;
    const float* base = xz + (size_t)(b * SEQL) * 768 + e;
    float w0 = cw[e * 4], w1 = cw[e * 4 + 1], w2 = cw[e * 4 + 2], w3 = cw[e * 4 + 3];
    float acc = cb[e];
    if (l >= 3) acc = fmaf(base[(size_t)(l - 3) * 768], w0, acc);
    if (l >= 2) acc = fmaf(base[(size_t)(l - 2) * 768], w1, acc);
    if (l >= 1) acc = fmaf(base[(size_t)(l - 1) * 768], w2, acc);
    acc = fmaf(base[(size_t)l * 768], w3, acc);
    xc[idx] = acc * sigmoidf_(acc);
}

// ---------------- wave-parallel chunked selective scan ----------------
// One WAVE per (b, e) chain. Lane j owns l in [4j, 4j+4), j<49 active.
// Pass 1: local affine transform (P = prod dA, H = local scan), dA/du cached in regs.
// Kogge-Stone shuffle scan composes transforms across lanes; pass 2 replays with
// the correct incoming state (no exp recompute) and emits gated y.
// grid (64, 96), block 256 (= 4 waves = 4 e-values; x_dbl[b] staged once in LDS).
__global__ __launch_bounds__(256) void scan_kernel(const float* __restrict__ xdbl,
        const float* __restrict__ xc, const float* __restrict__ xz,
        const float* __restrict__ dtw, const float* __restrict__ dtb,
        const float* __restrict__ a_log, const float* __restrict__ Dp, float* __restrict__ y) {
    __shared__ float sd[SEQL * 44];
    int b = blockIdx.x;
    int e = blockIdx.y * 4 + (threadIdx.x >> 6);
    int lane = threadIdx.x & 63;
    const float* src = xdbl + (size_t)b * SEQL * 44;
    for (int i = threadIdx.x; i < SEQL * 44; i += 256) sd[i] = src[i];
    __syncthreads();

    float wdt[DR];
    #pragma unroll
    for (int j = 0; j < DR; j++) wdt[j] = dtw[(size_t)e * DR + j];
    float db = dtb[e], Dv = Dp[e];

    bool act = lane < 49;
    int l0 = lane * 4;

    float P[DS], h[DS], dAs[4][DS], du4[4], xcv4[4], zv4[4];
    #pragma unroll
    for (int n = 0; n < DS; n++) { P[n] = 1.f; h[n] = 0.f; }

    if (act) {
        float Av[DS];
        #pragma unroll
        for (int n = 0; n < DS; n++) Av[n] = -__expf(a_log[(size_t)e * DS + n]);
        #pragma unroll
        for (int s = 0; s < 4; s++) {
            int l = l0 + s;
            const float* row = &sd[l * 44];
            float d = db;
            #pragma unroll
            for (int j = 0; j < DR; j++) d = fmaf(row[j], wdt[j], d);
            d = (d > 20.f) ? d : log1pf(__expf(d));  // softplus
            float xcv = xc[(size_t)(b * SEQL + l) * DI + e];
            float zv  = xz[(size_t)(b * SEQL + l) * 768 + DI + e];
            xcv4[s] = xcv; zv4[s] = zv;
            float du = d * xcv;
            du4[s] = du;
            #pragma unroll
            for (int n = 0; n < DS; n++) {
                float dA = __expf(d * Av[n]);
                dAs[s][n] = dA;
                h[n] = fmaf(h[n], dA, du * row[12 + n]);
                P[n] *= dA;
            }
        }
    }

    // Kogge-Stone inclusive scan of affine maps across lanes.
    #pragma unroll
    for (int off = 1; off < 64; off <<= 1) {
        #pragma unroll
        for (int n = 0; n < DS; n++) {
            float Pp = __shfl_up(P[n], off);
            float Hp = __shfl_up(h[n], off);
            if (lane >= off) {
                h[n] = fmaf(P[n], Hp, h[n]);
                P[n] *= Pp;
            }
        }
    }
    // Exclusive: state entering this lane's chunk.
    #pragma unroll
    for (int n = 0; n < DS; n++) {
        float Hp = __shfl_up(h[n], 1);
        h[n] = (lane == 0) ? 0.f : Hp;
    }

    if (act) {
        #pragma unroll
        for (int s = 0; s < 4; s++) {
            int l = l0 + s;
            const float* row = &sd[l * 44];
            float du = du4[s];
            float acc = 0.f;
            #pragma unroll
            for (int n = 0; n < DS; n++) {
                h[n] = fmaf(h[n], dAs[s][n], du * row[12 + n]);
                acc = fmaf(h[n], row[28 + n], acc);
            }
            float yv = fmaf(xcv4[s], Dv, acc);
            float zv = zv4[s];
            y[(size_t)(b * SEQL + l) * DI + e] = yv * zv * sigmoidf_(zv);
        }
    }
}

// ---------------- mean over L ----------------
__global__ void pool_kernel(const float* __restrict__ normed, float* __restrict__ pooled) {
    int b = blockIdx.x, d = threadIdx.x;
    float s = 0.f;
    for (int l = 0; l < SEQL; l++) s += normed[(size_t)(b * SEQL + l) * DM + d];
    pooled[b * DM + d] = s * (1.f / 196.f);
}

extern "C" void kernel_launch(void* const* d_in, const int* in_sizes, int n_in,
                              void* d_out, int out_size, void* d_ws, size_t ws_size,
                              hipStream_t stream) {
    const float* x       = (const float*)d_in[0];
    const float* patch_w = (const float*)d_in[1];
    const float* patch_b = (const float*)d_in[2];
    const float* norm_w  = (const float*)d_in[3];
    const float* norm_b  = (const float*)d_in[4];
    const float* in_w    = (const float*)d_in[5];
    const float* conv_w  = (const float*)d_in[6];
    const float* conv_b  = (const float*)d_in[7];
    const float* xp_w    = (const float*)d_in[8];
    const float* dt_w    = (const float*)d_in[9];
    const float* dt_b    = (const float*)d_in[10];
    const float* A_log   = (const float*)d_in[11];
    const float* Dp      = (const float*)d_in[12];
    const float* out_w   = (const float*)d_in[13];
    const float* normf_w = (const float*)d_in[14];
    const float* normf_b = (const float*)d_in[15];
    const float* head_w  = (const float*)d_in[16];
    const float* head_b  = (const float*)d_in[17];

    float* ws = (float*)d_ws;
    float* residual = ws;                    // 12544*192
    float* hidden   = ws + 2408448;
    float* normed   = ws + 4816896;
    float* xz       = ws + 7225344;          // 12544*768
    float* xc       = ws + 16859136;         // 12544*384
    float* yb       = ws + 21676032;         // 12544*384
    float* xdbl     = ws + 26492928;         // 12544*44
    float* pooled   = ws + 27044864;         // 64*192

    hipMemsetAsync(residual, 0, (size_t)2408448 * sizeof(float), stream);

    gemm_patch<<<dim3(98, 2), 256, 0, stream>>>(x, patch_w, patch_b, hidden);

    for (int d = 0; d < DEPTH; ++d) {
        ln_kernel<<<3136, 256, 0, stream>>>(residual, hidden, norm_w + d * DM, norm_b + d * DM, normed);
        gemm128<false><<<dim3(98, 6), 256, 0, stream>>>(normed, in_w + (size_t)d * 768 * 192, nullptr,
                                                        xz, 768, 192);
        conv_silu_kernel<<<18816, 256, 0, stream>>>(xz, conv_w + d * DI * 4, conv_b + d * DI, xc);
        gemm64<false><<<dim3(196, 1), 256, 0, stream>>>(xc, xp_w + (size_t)d * 44 * 384, nullptr,
                                                        xdbl, MROWS, 44, 384);
        scan_kernel<<<dim3(64, 96), 256, 0, stream>>>(xdbl, xc, xz, dt_w + d * DI * DR, dt_b + d * DI,
                                                      A_log + d * DI * DS, Dp + d * DI, yb);
        gemm128<false><<<dim3(98, 2), 256, 0, stream>>>(yb, out_w + (size_t)d * 192 * 384, nullptr,
                                                        hidden, 192, 384);
    }

    ln_kernel<<<3136, 256, 0, stream>>>(residual, hidden, normf_w, normf_b, normed);
    pool_kernel<<<64, 192, 0, stream>>>(normed, pooled);
    gemm64<true><<<dim3(1, 16), 256, 0, stream>>>(pooled, head_w, head_b, (float*)d_out, 64, 1000, 192);
}

// Round 3
// 4123.318 us; speedup vs baseline: 1.7457x; 1.5124x over previous
//
#include <hip/hip_runtime.h>
#include <math.h>

// VisionMamba forward. Round 3: bf16 MFMA for in_proj/out_proj GEMMs.
// B=64, L=196, D_MODEL=192, D_INNER=384, D_STATE=16, DT_RANK=12, DEPTH=24.

#define DEPTH 24
#define DM 192
#define DI 384
#define DS 16
#define DR 12
#define SEQL 196
#define BATCH 64
#define MROWS (BATCH*SEQL)   // 12544

typedef unsigned short ushort_t;
typedef __bf16 bf16x8 __attribute__((ext_vector_type(8)));
typedef float f32x4 __attribute__((ext_vector_type(4)));

__device__ __forceinline__ float sigmoidf_(float x) { return 1.f / (1.f + __expf(-x)); }

__device__ __forceinline__ ushort_t f2bf(float f) {  // RNE fp32->bf16
    union { float f; unsigned u; } c; c.f = f;
    unsigned u = c.u;
    return (ushort_t)((u + 0x7FFFu + ((u >> 16) & 1u)) >> 16);
}

__device__ __forceinline__ void load_lds16(const ushort_t* g, ushort_t* l) {
    // 16B global -> LDS DMA; LDS dest is wave-uniform base + lane*16.
    __builtin_amdgcn_global_load_lds((__attribute__((address_space(1))) void*)g,
                                     (__attribute__((address_space(3))) void*)l, 16, 0, 0);
}

// ---------------- fp32 -> bf16 bulk convert (weights), 4 elems/thread ----------------
__global__ void f2bf4_kernel(const float* __restrict__ src, ushort_t* __restrict__ dst, int n4) {
    int i = blockIdx.x * 256 + threadIdx.x;
    if (i >= n4) return;
    float4 v = ((const float4*)src)[i];
    union { ushort_t s[4]; uint2 u; } o;
    o.s[0] = f2bf(v.x); o.s[1] = f2bf(v.y); o.s[2] = f2bf(v.z); o.s[3] = f2bf(v.w);
    ((uint2*)dst)[i] = o.u;
}

// ---------------- residual += hidden; out = LayerNorm(residual) ----------------
// BF=true: out is bf16 (feeds MFMA GEMM). BF=false: out fp32.
template<bool BF>
__global__ void ln_kernel(float* __restrict__ residual, const float* __restrict__ hidden,
                          const float* __restrict__ w, const float* __restrict__ b,
                          void* __restrict__ out_) {
    int wave = threadIdx.x >> 6, lane = threadIdx.x & 63;
    int row = blockIdx.x * 4 + wave;
    float* rr = residual + (size_t)row * DM;
    const float* hr = hidden + (size_t)row * DM;
    float v0 = rr[lane]       + hr[lane];
    float v1 = rr[lane + 64]  + hr[lane + 64];
    float v2 = rr[lane + 128] + hr[lane + 128];
    rr[lane] = v0; rr[lane + 64] = v1; rr[lane + 128] = v2;
    float s = v0 + v1 + v2;
    #pragma unroll
    for (int off = 32; off > 0; off >>= 1) s += __shfl_down(s, off);
    float mean = __shfl(s, 0) * (1.f / DM);
    float d0 = v0 - mean, d1 = v1 - mean, d2 = v2 - mean;
    float q = d0 * d0 + d1 * d1 + d2 * d2;
    #pragma unroll
    for (int off = 32; off > 0; off >>= 1) q += __shfl_down(q, off);
    float rstd = rsqrtf(__shfl(q, 0) * (1.f / DM) + 1e-5f);
    float o0 = d0 * rstd * w[lane]       + b[lane];
    float o1 = d1 * rstd * w[lane + 64]  + b[lane + 64];
    float o2 = d2 * rstd * w[lane + 128] + b[lane + 128];
    if constexpr (BF) {
        ushort_t* o = (ushort_t*)out_ + (size_t)row * DM;
        o[lane] = f2bf(o0); o[lane + 64] = f2bf(o1); o[lane + 128] = f2bf(o2);
    } else {
        float* o = (float*)out_ + (size_t)row * DM;
        o[lane] = o0; o[lane + 64] = o1; o[lane + 128] = o2;
    }
}

// ---------------- bf16 MFMA GEMM: C[M,N] fp32 = A[M,K]bf16 * W[N,K]bf16^T ----------------
// BM=128 fixed. Block 256 = 4 waves in WM x WN grid; wave tile = (128/WM) x (BN/WN),
// frags FM x FN of 16x16, K-step 32. LDS slots (16B chunks) XOR-swizzled:
// slot(row,quad) = row*4 + (quad ^ ((row>>1)&3)) -> frag b128 reads are 2-way (free).
// Staging uses global_load_lds width=16: lane l of wave w fills slot w*64+l (+256).
// Requires M%128==0, N%BN==0, K%32==0 (all exact for our shapes).
template<int BN, int WM, int WN>
__global__ __launch_bounds__(256, 2) void gemm_mfma(const ushort_t* __restrict__ A,
        const ushort_t* __restrict__ W, float* __restrict__ C, int N, int K) {
    constexpr int FM = 128 / (WM * 16);
    constexpr int FN = BN / (WN * 16);
    __shared__ ushort_t sA[128 * 32];
    __shared__ ushort_t sB[BN * 32];
    const int t = threadIdx.x;
    const int wave = t >> 6, lane = t & 63;
    const int lr = lane & 15, lq = lane >> 4;
    const int wr = wave / WN, wc = wave % WN;
    const int m0 = blockIdx.x * 128, n0 = blockIdx.y * BN;
    const int wbase = t & ~63;   // wave*64

    f32x4 acc[FM][FN];
    #pragma unroll
    for (int i = 0; i < FM; i++)
        #pragma unroll
        for (int j = 0; j < FN; j++) acc[i][j] = f32x4{0.f, 0.f, 0.f, 0.f};

    for (int k0 = 0; k0 < K; k0 += 32) {
        __syncthreads();
        #pragma unroll
        for (int c = 0; c < 2; c++) {           // A: 512 slots
            int s = c * 256 + t;
            int row = s >> 2;
            int quad = (s & 3) ^ ((row >> 1) & 3);
            load_lds16(A + (size_t)(m0 + row) * K + k0 + quad * 8,
                       sA + (size_t)(c * 256 + wbase) * 8);
        }
        #pragma unroll
        for (int c = 0; c < BN * 4 / 256; c++) { // B: BN*4 slots
            int s = c * 256 + t;
            int row = s >> 2;
            int quad = (s & 3) ^ ((row >> 1) & 3);
            load_lds16(W + (size_t)(n0 + row) * K + k0 + quad * 8,
                       sB + (size_t)(c * 256 + wbase) * 8);
        }
        __syncthreads();
        bf16x8 af[FM], bfr[FN];
        #pragma unroll
        for (int i = 0; i < FM; i++) {
            int row = wr * FM * 16 + i * 16 + lr;
            int slot = (row << 2) | (lq ^ ((row >> 1) & 3));
            af[i] = *(const bf16x8*)&sA[(size_t)slot * 8];
        }
        #pragma unroll
        for (int j = 0; j < FN; j++) {
            int row = wc * FN * 16 + j * 16 + lr;
            int slot = (row << 2) | (lq ^ ((row >> 1) & 3));
            bfr[j] = *(const bf16x8*)&sB[(size_t)slot * 8];
        }
        #pragma unroll
        for (int i = 0; i < FM; i++)
            #pragma unroll
            for (int j = 0; j < FN; j++)
                acc[i][j] = __builtin_amdgcn_mfma_f32_16x16x32_bf16(af[i], bfr[j], acc[i][j], 0, 0, 0);
    }
    // C/D layout: col = lane&15, row = (lane>>4)*4 + reg  [m89/m91-verified]
    int crow0 = m0 + wr * FM * 16 + lq * 4;
    int ccol0 = n0 + wc * FN * 16 + lr;
    #pragma unroll
    for (int i = 0; i < FM; i++)
        #pragma unroll
        for (int j = 0; j < FN; j++) {
            float* cp = C + (size_t)(crow0 + i * 16) * N + ccol0 + j * 16;
            #pragma unroll
            for (int r = 0; r < 4; r++) cp[(size_t)r * N] = acc[i][j][r];
        }
}

// ---------------- Patch-embed GEMM (fp32, unchanged) ----------------
__global__ __launch_bounds__(256, 2) void gemm_patch(const float* __restrict__ X,
        const float* __restrict__ W, const float* __restrict__ bias, float* __restrict__ C) {
    const int N = 192, K = 768;
    __shared__ float As[16][132];
    __shared__ float Ws[16][132];
    int t = threadIdx.x;
    int m0 = blockIdx.x * 128, n0 = blockIdx.y * 128;
    int lr = t >> 1, lk = (t & 1) * 4;
    int m = m0 + lr;
    int b = m / 196, r = m % 196, py = r / 14, px = r % 14;
    const float* xb = X + (size_t)b * 150528 + py * 3584 + px * 16;
    int wn = n0 + lr;
    bool wv = wn < N;
    const float* Wp = W + (size_t)(wv ? wn : 0) * K + lk;
    int tm = (t >> 4) * 8, tn = (t & 15) * 8;
    float acc[8][8];
    #pragma unroll
    for (int i = 0; i < 8; i++)
        #pragma unroll
        for (int j = 0; j < 8; j++) acc[i][j] = 0.f;

    for (int k0 = 0; k0 < 768; k0 += 16) {
        int k = k0 + lk;
        int ci = k >> 8, ky = (k >> 4) & 15;
        const float* p = xb + ci * 50176 + ky * 224 + (k & 15);
        float4 a0 = *(const float4*)p;
        float4 a1 = *(const float4*)(p + 8);
        float4 w0 = make_float4(0.f, 0.f, 0.f, 0.f), w1 = w0;
        if (wv) { w0 = *(const float4*)(Wp + k0); w1 = *(const float4*)(Wp + k0 + 8); }
        __syncthreads();
        As[lk + 0][lr] = a0.x; As[lk + 1][lr] = a0.y; As[lk + 2][lr] = a0.z; As[lk + 3][lr] = a0.w;
        As[lk + 8][lr] = a1.x; As[lk + 9][lr] = a1.y; As[lk + 10][lr] = a1.z; As[lk + 11][lr] = a1.w;
        Ws[lk + 0][lr] = w0.x; Ws[lk + 1][lr] = w0.y; Ws[lk + 2][lr] = w0.z; Ws[lk + 3][lr] = w0.w;
        Ws[lk + 8][lr] = w1.x; Ws[lk + 9][lr] = w1.y; Ws[lk + 10][lr] = w1.z; Ws[lk + 11][lr] = w1.w;
        __syncthreads();
        #pragma unroll
        for (int kk = 0; kk < 16; kk++) {
            float4 x0 = *(const float4*)&As[kk][tm];
            float4 x1 = *(const float4*)&As[kk][tm + 4];
            float4 y0 = *(const float4*)&Ws[kk][tn];
            float4 y1 = *(const float4*)&Ws[kk][tn + 4];
            float av[8] = {x0.x, x0.y, x0.z, x0.w, x1.x, x1.y, x1.z, x1.w};
            float bv[8] = {y0.x, y0.y, y0.z, y0.w, y1.x, y1.y, y1.z, y1.w};
            #pragma unroll
            for (int i = 0; i < 8; i++)
                #pragma unroll
                for (int j = 0; j < 8; j++) acc[i][j] = fmaf(av[i], bv[j], acc[i][j]);
        }
    }
    #pragma unroll
    for (int i = 0; i < 8; i++) {
        float* cr = C + (size_t)(m0 + tm + i) * N;
        #pragma unroll
        for (int jv = 0; jv < 8; jv += 4) {
            int n = n0 + tn + jv;
            if (n < N) {
                float4 v = {acc[i][jv] + bias[n], acc[i][jv + 1] + bias[n + 1],
                            acc[i][jv + 2] + bias[n + 2], acc[i][jv + 3] + bias[n + 3]};
                *(float4*)(cr + n) = v;
            }
        }
    }
}

// ---------------- Small fp32 GEMM (x_proj, head) ----------------
template<bool BIAS>
__global__ __launch_bounds__(256, 2) void gemm64(const float* __restrict__ A,
        const float* __restrict__ W, const float* __restrict__ bias,
        float* __restrict__ C, int M, int N, int K) {
    __shared__ float As[32][68];
    __shared__ float Ws[32][68];
    int t = threadIdx.x;
    int m0 = blockIdx.x * 64, n0 = blockIdx.y * 64;
    int lr = t >> 2, lk = (t & 3) * 4;
    int am = m0 + lr; bool avld = am < M;
    const float* Ap = A + (size_t)(avld ? am : 0) * K + lk;
    int wn = n0 + lr; bool wv = wn < N;
    const float* Wp = W + (size_t)(wv ? wn : 0) * K + lk;
    int tm = (t >> 4) * 4, tn = (t & 15) * 4;
    float acc[4][4];
    #pragma unroll
    for (int i = 0; i < 4; i++)
        #pragma unroll
        for (int j = 0; j < 4; j++) acc[i][j] = 0.f;

    for (int k0 = 0; k0 < K; k0 += 32) {
        float4 a0 = make_float4(0.f, 0.f, 0.f, 0.f), a1 = a0, w0 = a0, w1 = a0;
        if (avld) { a0 = *(const float4*)(Ap + k0); a1 = *(const float4*)(Ap + k0 + 16); }
        if (wv)   { w0 = *(const float4*)(Wp + k0); w1 = *(const float4*)(Wp + k0 + 16); }
        __syncthreads();
        As[lk + 0][lr] = a0.x; As[lk + 1][lr] = a0.y; As[lk + 2][lr] = a0.z; As[lk + 3][lr] = a0.w;
        As[lk + 16][lr] = a1.x; As[lk + 17][lr] = a1.y; As[lk + 18][lr] = a1.z; As[lk + 19][lr] = a1.w;
        Ws[lk + 0][lr] = w0.x; Ws[lk + 1][lr] = w0.y; Ws[lk + 2][lr] = w0.z; Ws[lk + 3][lr] = w0.w;
        Ws[lk + 16][lr] = w1.x; Ws[lk + 17][lr] = w1.y; Ws[lk + 18][lr] = w1.z; Ws[lk + 19][lr] = w1.w;
        __syncthreads();
        #pragma unroll
        for (int kk = 0; kk < 32; kk++) {
            float4 x0 = *(const float4*)&As[kk][tm];
            float4 y0 = *(const float4*)&Ws[kk][tn];
            float av[4] = {x0.x, x0.y, x0.z, x0.w};
            float bv[4] = {y0.x, y0.y, y0.z, y0.w};
            #pragma unroll
            for (int i = 0; i < 4; i++)
                #pragma unroll
                for (int j = 0; j < 4; j++) acc[i][j] = fmaf(av[i], bv[j], acc[i][j]);
        }
    }
    #pragma unroll
    for (int i = 0; i < 4; i++) {
        int m = m0 + tm + i;
        if (m >= M) continue;
        float* cr = C + (size_t)m * N;
        int n = n0 + tn;
        if (n < N) {
            float4 v = {acc[i][0], acc[i][1], acc[i][2], acc[i][3]};
            if (BIAS) { v.x += bias[n]; v.y += bias[n + 1]; v.z += bias[n + 2]; v.w += bias[n + 3]; }
            *(float4*)(cr + n) = v;
        }
    }
}

// ---------------- depthwise causal conv(4) + SiLU ----------------
__global__ void conv_silu_kernel(const float* __restrict__ xz, const float* __restrict__ cw,
                                 const float* __restrict__ cb, float* __restrict__ xc) {
    int idx = blockIdx.x * 256 + threadIdx.x;
    if (idx >= MROWS * DI) return;
    int e = idx % DI; int bl = idx / DI; int l = bl % SEQL; int b = bl / SEQL;
    const float* base = xz + (size_t)(b * SEQL) * 768 + e;
    float w0 = cw[e * 4], w1 = cw[e * 4 + 1], w2 = cw[e * 4 + 2], w3 = cw[e * 4 + 3];
    float acc = cb[e];
    if (l >= 3) acc = fmaf(base[(size_t)(l - 3) * 768], w0, acc);
    if (l >= 2) acc = fmaf(base[(size_t)(l - 2) * 768], w1, acc);
    if (l >= 1) acc = fmaf(base[(size_t)(l - 1) * 768], w2, acc);
    acc = fmaf(base[(size_t)l * 768], w3, acc);
    xc[idx] = acc * sigmoidf_(acc);
}

// ---------------- wave-parallel chunked selective scan (bf16 y out) ----------------
__global__ __launch_bounds__(256) void scan_kernel(const float* __restrict__ xdbl,
        const float* __restrict__ xc, const float* __restrict__ xz,
        const float* __restrict__ dtw, const float* __restrict__ dtb,
        const float* __restrict__ a_log, const float* __restrict__ Dp, ushort_t* __restrict__ y) {
    __shared__ float sd[SEQL * 44];
    int b = blockIdx.x;
    int e = blockIdx.y * 4 + (threadIdx.x >> 6);
    int lane = threadIdx.x & 63;
    const float* src = xdbl + (size_t)b * SEQL * 44;
    for (int i = threadIdx.x; i < SEQL * 44; i += 256) sd[i] = src[i];
    __syncthreads();

    float wdt[DR];
    #pragma unroll
    for (int j = 0; j < DR; j++) wdt[j] = dtw[(size_t)e * DR + j];
    float db = dtb[e], Dv = Dp[e];

    bool act = lane < 49;
    int l0 = lane * 4;

    float P[DS], h[DS], dAs[4][DS], du4[4], xcv4[4], zv4[4];
    #pragma unroll
    for (int n = 0; n < DS; n++) { P[n] = 1.f; h[n] = 0.f; }

    if (act) {
        float Av[DS];
        #pragma unroll
        for (int n = 0; n < DS; n++) Av[n] = -__expf(a_log[(size_t)e * DS + n]);
        #pragma unroll
        for (int s = 0; s < 4; s++) {
            int l = l0 + s;
            const float* row = &sd[l * 44];
            float d = db;
            #pragma unroll
            for (int j = 0; j < DR; j++) d = fmaf(row[j], wdt[j], d);
            d = (d > 20.f) ? d : log1pf(__expf(d));  // softplus
            float xcv = xc[(size_t)(b * SEQL + l) * DI + e];
            float zv  = xz[(size_t)(b * SEQL + l) * 768 + DI + e];
            xcv4[s] = xcv; zv4[s] = zv;
            float du = d * xcv;
            du4[s] = du;
            #pragma unroll
            for (int n = 0; n < DS; n++) {
                float dA = __expf(d * Av[n]);
                dAs[s][n] = dA;
                h[n] = fmaf(h[n], dA, du * row[12 + n]);
                P[n] *= dA;
            }
        }
    }

    #pragma unroll
    for (int off = 1; off < 64; off <<= 1) {
        #pragma unroll
        for (int n = 0; n < DS; n++) {
            float Pp = __shfl_up(P[n], off);
            float Hp = __shfl_up(h[n], off);
            if (lane >= off) {
                h[n] = fmaf(P[n], Hp, h[n]);
                P[n] *= Pp;
            }
        }
    }
    #pragma unroll
    for (int n = 0; n < DS; n++) {
        float Hp = __shfl_up(h[n], 1);
        h[n] = (lane == 0) ? 0.f : Hp;
    }

    if (act) {
        #pragma unroll
        for (int s = 0; s < 4; s++) {
            int l = l0 + s;
            const float* row = &sd[l * 44];
            float du = du4[s];
            float acc = 0.f;
            #pragma unroll
            for (int n = 0; n < DS; n++) {
                h[n] = fmaf(h[n], dAs[s][n], du * row[12 + n]);
                acc = fmaf(h[n], row[28 + n], acc);
            }
            float yv = fmaf(xcv4[s], Dv, acc);
            float zv = zv4[s];
            y[(size_t)(b * SEQL + l) * DI + e] = f2bf(yv * zv * sigmoidf_(zv));
        }
    }
}

// ---------------- mean over L ----------------
__global__ void pool_kernel(const float* __restrict__ normed, float* __restrict__ pooled) {
    int b = blockIdx.x, d = threadIdx.x;
    float s = 0.f;
    for (int l = 0; l < SEQL; l++) s += normed[(size_t)(b * SEQL + l) * DM + d];
    pooled[b * DM + d] = s * (1.f / 196.f);
}

extern "C" void kernel_launch(void* const* d_in, const int* in_sizes, int n_in,
                              void* d_out, int out_size, void* d_ws, size_t ws_size,
                              hipStream_t stream) {
    const float* x       = (const float*)d_in[0];
    const float* patch_w = (const float*)d_in[1];
    const float* patch_b = (const float*)d_in[2];
    const float* norm_w  = (const float*)d_in[3];
    const float* norm_b  = (const float*)d_in[4];
    const float* in_w    = (const float*)d_in[5];
    const float* conv_w  = (const float*)d_in[6];
    const float* conv_b  = (const float*)d_in[7];
    const float* xp_w    = (const float*)d_in[8];
    const float* dt_w    = (const float*)d_in[9];
    const float* dt_b    = (const float*)d_in[10];
    const float* A_log   = (const float*)d_in[11];
    const float* Dp      = (const float*)d_in[12];
    const float* out_w   = (const float*)d_in[13];
    const float* normf_w = (const float*)d_in[14];
    const float* normf_b = (const float*)d_in[15];
    const float* head_w  = (const float*)d_in[16];
    const float* head_b  = (const float*)d_in[17];

    float* ws = (float*)d_ws;
    float* residual   = ws;                       // 2,408,448 f
    float* hidden     = ws + 2408448;             // 2,408,448 f
    float* xz         = ws + 4816896;             // 9,633,792 f
    float* xc         = ws + 14450688;            // 4,816,896 f
    float* xdbl       = ws + 19267584;            //   552,960 f (pad)
    float* pooled     = ws + 19820544;            //    12,288 f
    ushort_t* normed_bf = (ushort_t*)(ws + 19832832);  // 2,408,448 u16
    ushort_t* y_bf      = (ushort_t*)(ws + 21037056);  // 4,816,896 u16
    ushort_t* in_w_bf   = (ushort_t*)(ws + 23445504);  // 3,538,944 u16
    ushort_t* out_w_bf  = (ushort_t*)(ws + 25214976);  // 1,769,472 u16
    // total 26,099,712 floats = 104.4 MB

    hipMemsetAsync(residual, 0, (size_t)2408448 * sizeof(float), stream);

    // weights -> bf16 (once per launch)
    f2bf4_kernel<<<3456, 256, 0, stream>>>(in_w, in_w_bf, 884736);
    f2bf4_kernel<<<1728, 256, 0, stream>>>(out_w, out_w_bf, 442368);

    gemm_patch<<<dim3(98, 2), 256, 0, stream>>>(x, patch_w, patch_b, hidden);

    for (int d = 0; d < DEPTH; ++d) {
        ln_kernel<true><<<3136, 256, 0, stream>>>(residual, hidden, norm_w + d * DM,
                                                  norm_b + d * DM, normed_bf);
        // in_proj: [12544,192]bf16 x [768,192]bf16^T -> xz fp32
        gemm_mfma<128, 2, 2><<<dim3(98, 6), 256, 0, stream>>>(normed_bf,
                in_w_bf + (size_t)d * 768 * 192, xz, 768, 192);
        conv_silu_kernel<<<18816, 256, 0, stream>>>(xz, conv_w + d * DI * 4, conv_b + d * DI, xc);
        gemm64<false><<<dim3(196, 1), 256, 0, stream>>>(xc, xp_w + (size_t)d * 44 * 384, nullptr,
                                                        xdbl, MROWS, 44, 384);
        scan_kernel<<<dim3(64, 96), 256, 0, stream>>>(xdbl, xc, xz, dt_w + d * DI * DR, dt_b + d * DI,
                                                      A_log + d * DI * DS, Dp + d * DI, y_bf);
        // out_proj: [12544,384]bf16 x [192,384]bf16^T -> hidden fp32
        gemm_mfma<64, 4, 1><<<dim3(98, 3), 256, 0, stream>>>(y_bf,
                out_w_bf + (size_t)d * 192 * 384, hidden, 192, 384);
    }

    ln_kernel<false><<<3136, 256, 0, stream>>>(residual, hidden, normf_w, normf_b, xz);
    pool_kernel<<<64, 192, 0, stream>>>(xz, pooled);
    gemm64<true><<<dim3(1, 16), 256, 0, stream>>>(pooled, head_w, head_b, (float*)d_out, 64, 1000, 192);
}

// Round 4
// 4080.436 us; speedup vs baseline: 1.7640x; 1.0105x over previous
//
#include <hip/hip_runtime.h>
#include <math.h>

// VisionMamba forward. Round 4: all large GEMMs on bf16 MFMA (patch, in_proj,
// x_proj, out_proj); conv emits bf16; xdbl stride 49 (LDS-conflict-free scan).
// B=64, L=196, D_MODEL=192, D_INNER=384, D_STATE=16, DT_RANK=12, DEPTH=24.

#define DEPTH 24
#define DM 192
#define DI 384
#define DS 16
#define DR 12
#define SEQL 196
#define BATCH 64
#define MROWS (BATCH*SEQL)   // 12544
#define XDS 49               // xdbl row stride (odd -> conflict-free LDS rows)

typedef unsigned short ushort_t;
typedef __bf16 bf16x8 __attribute__((ext_vector_type(8)));
typedef float f32x4 __attribute__((ext_vector_type(4)));

__device__ __forceinline__ float sigmoidf_(float x) { return 1.f / (1.f + __expf(-x)); }

__device__ __forceinline__ ushort_t f2bf(float f) {  // RNE fp32->bf16
    union { float f; unsigned u; } c; c.f = f;
    unsigned u = c.u;
    return (ushort_t)((u + 0x7FFFu + ((u >> 16) & 1u)) >> 16);
}
__device__ __forceinline__ float bf2f(ushort_t u) {
    union { unsigned u; float f; } c; c.u = ((unsigned)u) << 16;
    return c.f;
}

__device__ __forceinline__ void load_lds16(const ushort_t* g, ushort_t* l) {
    __builtin_amdgcn_global_load_lds((__attribute__((address_space(1))) void*)g,
                                     (__attribute__((address_space(3))) void*)l, 16, 0, 0);
}

// ---------------- fp32 -> bf16 bulk convert, 4 elems/thread ----------------
__global__ void f2bf4_kernel(const float* __restrict__ src, ushort_t* __restrict__ dst, int n4) {
    int i = blockIdx.x * 256 + threadIdx.x;
    if (i >= n4) return;
    float4 v = ((const float4*)src)[i];
    union { ushort_t s[4]; uint2 u; } o;
    o.s[0] = f2bf(v.x); o.s[1] = f2bf(v.y); o.s[2] = f2bf(v.z); o.s[3] = f2bf(v.w);
    ((uint2*)dst)[i] = o.u;
}

// xp_w [24][44][384] -> padded bf16 [24][64][384], rows 44..63 = 0
__global__ void xp_pad_kernel(const float* __restrict__ src, ushort_t* __restrict__ dst) {
    int i = blockIdx.x * 256 + threadIdx.x;
    if (i >= DEPTH * 64 * 384) return;
    int col = i % 384, row = (i / 384) & 63, d = i / (384 * 64);
    float v = (row < 44) ? src[(size_t)d * 44 * 384 + row * 384 + col] : 0.f;
    dst[i] = f2bf(v);
}

// ---------------- residual += hidden; out = LayerNorm(residual) ----------------
template<bool BF>
__global__ void ln_kernel(float* __restrict__ residual, const float* __restrict__ hidden,
                          const float* __restrict__ w, const float* __restrict__ b,
                          void* __restrict__ out_) {
    int wave = threadIdx.x >> 6, lane = threadIdx.x & 63;
    int row = blockIdx.x * 4 + wave;
    float* rr = residual + (size_t)row * DM;
    const float* hr = hidden + (size_t)row * DM;
    float v0 = rr[lane]       + hr[lane];
    float v1 = rr[lane + 64]  + hr[lane + 64];
    float v2 = rr[lane + 128] + hr[lane + 128];
    rr[lane] = v0; rr[lane + 64] = v1; rr[lane + 128] = v2;
    float s = v0 + v1 + v2;
    #pragma unroll
    for (int off = 32; off > 0; off >>= 1) s += __shfl_down(s, off);
    float mean = __shfl(s, 0) * (1.f / DM);
    float d0 = v0 - mean, d1 = v1 - mean, d2 = v2 - mean;
    float q = d0 * d0 + d1 * d1 + d2 * d2;
    #pragma unroll
    for (int off = 32; off > 0; off >>= 1) q += __shfl_down(q, off);
    float rstd = rsqrtf(__shfl(q, 0) * (1.f / DM) + 1e-5f);
    float o0 = d0 * rstd * w[lane]       + b[lane];
    float o1 = d1 * rstd * w[lane + 64]  + b[lane + 64];
    float o2 = d2 * rstd * w[lane + 128] + b[lane + 128];
    if constexpr (BF) {
        ushort_t* o = (ushort_t*)out_ + (size_t)row * DM;
        o[lane] = f2bf(o0); o[lane + 64] = f2bf(o1); o[lane + 128] = f2bf(o2);
    } else {
        float* o = (float*)out_ + (size_t)row * DM;
        o[lane] = o0; o[lane + 64] = o1; o[lane + 128] = o2;
    }
}

// ---------------- bf16 MFMA GEMM: C[M,*] = A[M,K]bf16 * W[N,K]bf16^T ----------------
// BM=128. 4 waves in WM x WN grid; frag tiles FM x FN of 16x16, K-step 32.
// LDS 16B slots XOR-swizzled: slot(row,quad)=row*4+(quad^((row>>1)&3)).
// NST: store col-tile (16-wide) only if its block-tile index < NST.
// Requires M%128==0, (gridDim.y*BN) <= N rows of W valid, K%32==0, BN*4%256 in {256,512,768}.
template<int BN, int WM, int WN, int NST>
__global__ __launch_bounds__(256, 2) void gemm_mfma(const ushort_t* __restrict__ A,
        const ushort_t* __restrict__ W, float* __restrict__ C, int K, int ldC) {
    constexpr int FM = 128 / (WM * 16);
    constexpr int FN = BN / (WN * 16);
    __shared__ ushort_t sA[128 * 32];
    __shared__ ushort_t sB[BN * 32];
    const int t = threadIdx.x;
    const int wave = t >> 6, lane = t & 63;
    const int lr = lane & 15, lq = lane >> 4;
    const int wr = wave / WN, wc = wave % WN;
    const int m0 = blockIdx.x * 128, n0 = blockIdx.y * BN;
    const int wbase = t & ~63;

    f32x4 acc[FM][FN];
    #pragma unroll
    for (int i = 0; i < FM; i++)
        #pragma unroll
        for (int j = 0; j < FN; j++) acc[i][j] = f32x4{0.f, 0.f, 0.f, 0.f};

    for (int k0 = 0; k0 < K; k0 += 32) {
        __syncthreads();
        #pragma unroll
        for (int c = 0; c < 2; c++) {           // A: 512 slots
            int s = c * 256 + t;
            int row = s >> 2;
            int quad = (s & 3) ^ ((row >> 1) & 3);
            load_lds16(A + (size_t)(m0 + row) * K + k0 + quad * 8,
                       sA + (size_t)(c * 256 + wbase) * 8);
        }
        #pragma unroll
        for (int c = 0; c < BN * 4 / 256; c++) { // B: BN*4 slots
            int s = c * 256 + t;
            int row = s >> 2;
            int quad = (s & 3) ^ ((row >> 1) & 3);
            load_lds16(W + (size_t)(n0 + row) * K + k0 + quad * 8,
                       sB + (size_t)(c * 256 + wbase) * 8);
        }
        __syncthreads();
        bf16x8 af[FM], bfr[FN];
        #pragma unroll
        for (int i = 0; i < FM; i++) {
            int row = wr * FM * 16 + i * 16 + lr;
            int slot = (row << 2) | (lq ^ ((row >> 1) & 3));
            af[i] = *(const bf16x8*)&sA[(size_t)slot * 8];
        }
        #pragma unroll
        for (int j = 0; j < FN; j++) {
            int row = wc * FN * 16 + j * 16 + lr;
            int slot = (row << 2) | (lq ^ ((row >> 1) & 3));
            bfr[j] = *(const bf16x8*)&sB[(size_t)slot * 8];
        }
        #pragma unroll
        for (int i = 0; i < FM; i++)
            #pragma unroll
            for (int j = 0; j < FN; j++)
                acc[i][j] = __builtin_amdgcn_mfma_f32_16x16x32_bf16(af[i], bfr[j], acc[i][j], 0, 0, 0);
    }
    // C/D layout: col = lane&15, row = (lane>>4)*4 + reg
    int crow0 = m0 + wr * FM * 16 + lq * 4;
    int ccol0 = n0 + wc * FN * 16 + lr;
    #pragma unroll
    for (int i = 0; i < FM; i++)
        #pragma unroll
        for (int j = 0; j < FN; j++) {
            if (wc * FN + j >= NST) continue;
            float* cp = C + (size_t)(crow0 + i * 16) * ldC + ccol0 + j * 16;
            #pragma unroll
            for (int r = 0; r < 4; r++) cp[(size_t)r * ldC] = acc[i][j][r];
        }
}

// ---------------- Patch-embed bf16 MFMA with im2col A-loader ----------------
// C[12544,192] = im2col(x_bf)[12544,768] * patch_w_bf[192,768]^T + patch_b
// BN=64, WM=4, WN=1, grid (98,3).
__global__ __launch_bounds__(256, 2) void gemm_patch_mfma(const ushort_t* __restrict__ Xbf,
        const ushort_t* __restrict__ Wbf, const float* __restrict__ bias, float* __restrict__ C) {
    constexpr int FM = 2, FN = 4;
    __shared__ ushort_t sA[128 * 32];
    __shared__ ushort_t sB[64 * 32];
    const int t = threadIdx.x;
    const int wave = t >> 6, lane = t & 63;
    const int lr = lane & 15, lq = lane >> 4;
    const int m0 = blockIdx.x * 128, n0 = blockIdx.y * 64;
    const int wbase = t & ~63;

    const ushort_t* abase[2];
    int aquad[2];
    #pragma unroll
    for (int c = 0; c < 2; c++) {
        int s = c * 256 + t;
        int row = s >> 2;
        aquad[c] = (s & 3) ^ ((row >> 1) & 3);
        int m = m0 + row;
        int b = m / 196, r = m % 196, py = r / 14, px = r % 14;
        abase[c] = Xbf + (size_t)b * 150528 + py * 3584 + px * 16;
    }
    int brow = t >> 2;
    int bquad = (t & 3) ^ ((brow >> 1) & 3);
    const ushort_t* bbase = Wbf + (size_t)(n0 + brow) * 768 + bquad * 8;

    f32x4 acc[FM][FN];
    #pragma unroll
    for (int i = 0; i < FM; i++)
        #pragma unroll
        for (int j = 0; j < FN; j++) acc[i][j] = f32x4{0.f, 0.f, 0.f, 0.f};

    for (int k0 = 0; k0 < 768; k0 += 32) {
        __syncthreads();
        #pragma unroll
        for (int c = 0; c < 2; c++) {
            int k = k0 + aquad[c] * 8;
            int ci = k >> 8, ky = (k >> 4) & 15, kx0 = k & 15;
            load_lds16(abase[c] + ci * 50176 + ky * 224 + kx0,
                       sA + (size_t)(c * 256 + wbase) * 8);
        }
        load_lds16(bbase + k0, sB + (size_t)wbase * 8);
        __syncthreads();
        bf16x8 af[FM], bfr[FN];
        #pragma unroll
        for (int i = 0; i < FM; i++) {
            int row = wave * FM * 16 + i * 16 + lr;
            int slot = (row << 2) | (lq ^ ((row >> 1) & 3));
            af[i] = *(const bf16x8*)&sA[(size_t)slot * 8];
        }
        #pragma unroll
        for (int j = 0; j < FN; j++) {
            int row = j * 16 + lr;
            int slot = (row << 2) | (lq ^ ((row >> 1) & 3));
            bfr[j] = *(const bf16x8*)&sB[(size_t)slot * 8];
        }
        #pragma unroll
        for (int i = 0; i < FM; i++)
            #pragma unroll
            for (int j = 0; j < FN; j++)
                acc[i][j] = __builtin_amdgcn_mfma_f32_16x16x32_bf16(af[i], bfr[j], acc[i][j], 0, 0, 0);
    }
    int crow0 = m0 + wave * FM * 16 + lq * 4;
    int ccol0 = n0 + lr;
    #pragma unroll
    for (int i = 0; i < FM; i++)
        #pragma unroll
        for (int j = 0; j < FN; j++) {
            int col = ccol0 + j * 16;
            float bv = bias[col];
            float* cp = C + (size_t)(crow0 + i * 16) * DM + col;
            #pragma unroll
            for (int r = 0; r < 4; r++) cp[(size_t)r * DM] = acc[i][j][r] + bv;
        }
}

// ---------------- Small fp32 GEMM (head only) ----------------
template<bool BIAS>
__global__ __launch_bounds__(256, 2) void gemm64(const float* __restrict__ A,
        const float* __restrict__ W, const float* __restrict__ bias,
        float* __restrict__ C, int M, int N, int K) {
    __shared__ float As[32][68];
    __shared__ float Ws[32][68];
    int t = threadIdx.x;
    int m0 = blockIdx.x * 64, n0 = blockIdx.y * 64;
    int lr = t >> 2, lk = (t & 3) * 4;
    int am = m0 + lr; bool avld = am < M;
    const float* Ap = A + (size_t)(avld ? am : 0) * K + lk;
    int wn = n0 + lr; bool wv = wn < N;
    const float* Wp = W + (size_t)(wv ? wn : 0) * K + lk;
    int tm = (t >> 4) * 4, tn = (t & 15) * 4;
    float acc[4][4];
    #pragma unroll
    for (int i = 0; i < 4; i++)
        #pragma unroll
        for (int j = 0; j < 4; j++) acc[i][j] = 0.f;

    for (int k0 = 0; k0 < K; k0 += 32) {
        float4 a0 = make_float4(0.f, 0.f, 0.f, 0.f), a1 = a0, w0 = a0, w1 = a0;
        if (avld) { a0 = *(const float4*)(Ap + k0); a1 = *(const float4*)(Ap + k0 + 16); }
        if (wv)   { w0 = *(const float4*)(Wp + k0); w1 = *(const float4*)(Wp + k0 + 16); }
        __syncthreads();
        As[lk + 0][lr] = a0.x; As[lk + 1][lr] = a0.y; As[lk + 2][lr] = a0.z; As[lk + 3][lr] = a0.w;
        As[lk + 16][lr] = a1.x; As[lk + 17][lr] = a1.y; As[lk + 18][lr] = a1.z; As[lk + 19][lr] = a1.w;
        Ws[lk + 0][lr] = w0.x; Ws[lk + 1][lr] = w0.y; Ws[lk + 2][lr] = w0.z; Ws[lk + 3][lr] = w0.w;
        Ws[lk + 16][lr] = w1.x; Ws[lk + 17][lr] = w1.y; Ws[lk + 18][lr] = w1.z; Ws[lk + 19][lr] = w1.w;
        __syncthreads();
        #pragma unroll
        for (int kk = 0; kk < 32; kk++) {
            float4 x0 = *(const float4*)&As[kk][tm];
            float4 y0 = *(const float4*)&Ws[kk][tn];
            float av[4] = {x0.x, x0.y, x0.z, x0.w};
            float bv[4] = {y0.x, y0.y, y0.z, y0.w};
            #pragma unroll
            for (int i = 0; i < 4; i++)
                #pragma unroll
                for (int j = 0; j < 4; j++) acc[i][j] = fmaf(av[i], bv[j], acc[i][j]);
        }
    }
    #pragma unroll
    for (int i = 0; i < 4; i++) {
        int m = m0 + tm + i;
        if (m >= M) continue;
        float* cr = C + (size_t)m * N;
        int n = n0 + tn;
        if (n < N) {
            float4 v = {acc[i][0], acc[i][1], acc[i][2], acc[i][3]};
            if (BIAS) { v.x += bias[n]; v.y += bias[n + 1]; v.z += bias[n + 2]; v.w += bias[n + 3]; }
            *(float4*)(cr + n) = v;
        }
    }
}

// ---------------- depthwise causal conv(4) + SiLU -> bf16 ----------------
__global__ void conv_silu_kernel(const float* __restrict__ xz, const float* __restrict__ cw,
                                 const float* __restrict__ cb, ushort_t* __restrict__ xcbf) {
    int idx = blockIdx.x * 256 + threadIdx.x;
    if (idx >= MROWS * DI) return;
    int e = idx % DI; int bl = idx / DI; int l = bl % SEQL; int b = bl / SEQL;
    const float* base = xz + (size_t)(b * SEQL) * 768 + e;
    float w0 = cw[e * 4], w1 = cw[e * 4 + 1], w2 = cw[e * 4 + 2], w3 = cw[e * 4 + 3];
    float acc = cb[e];
    if (l >= 3) acc = fmaf(base[(size_t)(l - 3) * 768], w0, acc);
    if (l >= 2) acc = fmaf(base[(size_t)(l - 2) * 768], w1, acc);
    if (l >= 1) acc = fmaf(base[(size_t)(l - 1) * 768], w2, acc);
    acc = fmaf(base[(size_t)l * 768], w3, acc);
    xcbf[idx] = f2bf(acc * sigmoidf_(acc));
}

// ---------------- wave-parallel chunked selective scan ----------------
// xdbl stride XDS=49 (odd): per-lane LDS row reads are conflict-free.
__global__ __launch_bounds__(256) void scan_kernel(const float* __restrict__ xdbl,
        const ushort_t* __restrict__ xcbf, const float* __restrict__ xz,
        const float* __restrict__ dtw, const float* __restrict__ dtb,
        const float* __restrict__ a_log, const float* __restrict__ Dp, ushort_t* __restrict__ y) {
    __shared__ float sd[SEQL * XDS];
    int b = blockIdx.x;
    int e = blockIdx.y * 4 + (threadIdx.x >> 6);
    int lane = threadIdx.x & 63;
    const float* src = xdbl + (size_t)b * SEQL * XDS;
    for (int i = threadIdx.x; i < SEQL * XDS; i += 256) sd[i] = src[i];
    __syncthreads();

    float wdt[DR];
    #pragma unroll
    for (int j = 0; j < DR; j++) wdt[j] = dtw[(size_t)e * DR + j];
    float db = dtb[e], Dv = Dp[e];

    bool act = lane < 49;
    int l0 = lane * 4;

    float P[DS], h[DS], dAs[4][DS], du4[4], xcv4[4], zv4[4];
    #pragma unroll
    for (int n = 0; n < DS; n++) { P[n] = 1.f; h[n] = 0.f; }

    if (act) {
        float Av[DS];
        #pragma unroll
        for (int n = 0; n < DS; n++) Av[n] = -__expf(a_log[(size_t)e * DS + n]);
        #pragma unroll
        for (int s = 0; s < 4; s++) {
            int l = l0 + s;
            const float* row = &sd[l * XDS];
            float d = db;
            #pragma unroll
            for (int j = 0; j < DR; j++) d = fmaf(row[j], wdt[j], d);
            d = (d > 20.f) ? d : log1pf(__expf(d));  // softplus
            float xcv = bf2f(xcbf[(size_t)(b * SEQL + l) * DI + e]);
            float zv  = xz[(size_t)(b * SEQL + l) * 768 + DI + e];
            xcv4[s] = xcv; zv4[s] = zv;
            float du = d * xcv;
            du4[s] = du;
            #pragma unroll
            for (int n = 0; n < DS; n++) {
                float dA = __expf(d * Av[n]);
                dAs[s][n] = dA;
                h[n] = fmaf(h[n], dA, du * row[12 + n]);
                P[n] *= dA;
            }
        }
    }

    #pragma unroll
    for (int off = 1; off < 64; off <<= 1) {
        #pragma unroll
        for (int n = 0; n < DS; n++) {
            float Pp = __shfl_up(P[n], off);
            float Hp = __shfl_up(h[n], off);
            if (lane >= off) {
                h[n] = fmaf(P[n], Hp, h[n]);
                P[n] *= Pp;
            }
        }
    }
    #pragma unroll
    for (int n = 0; n < DS; n++) {
        float Hp = __shfl_up(h[n], 1);
        h[n] = (lane == 0) ? 0.f : Hp;
    }

    if (act) {
        #pragma unroll
        for (int s = 0; s < 4; s++) {
            int l = l0 + s;
            const float* row = &sd[l * XDS];
            float du = du4[s];
            float acc = 0.f;
            #pragma unroll
            for (int n = 0; n < DS; n++) {
                h[n] = fmaf(h[n], dAs[s][n], du * row[12 + n]);
                acc = fmaf(h[n], row[28 + n], acc);
            }
            float yv = fmaf(xcv4[s], Dv, acc);
            float zv = zv4[s];
            y[(size_t)(b * SEQL + l) * DI + e] = f2bf(yv * zv * sigmoidf_(zv));
        }
    }
}

// ---------------- mean over L ----------------
__global__ void pool_kernel(const float* __restrict__ normed, float* __restrict__ pooled) {
    int b = blockIdx.x, d = threadIdx.x;
    float s = 0.f;
    for (int l = 0; l < SEQL; l++) s += normed[(size_t)(b * SEQL + l) * DM + d];
    pooled[b * DM + d] = s * (1.f / 196.f);
}

extern "C" void kernel_launch(void* const* d_in, const int* in_sizes, int n_in,
                              void* d_out, int out_size, void* d_ws, size_t ws_size,
                              hipStream_t stream) {
    const float* x       = (const float*)d_in[0];
    const float* patch_w = (const float*)d_in[1];
    const float* patch_b = (const float*)d_in[2];
    const float* norm_w  = (const float*)d_in[3];
    const float* norm_b  = (const float*)d_in[4];
    const float* in_w    = (const float*)d_in[5];
    const float* conv_w  = (const float*)d_in[6];
    const float* conv_b  = (const float*)d_in[7];
    const float* xp_w    = (const float*)d_in[8];
    const float* dt_w    = (const float*)d_in[9];
    const float* dt_b    = (const float*)d_in[10];
    const float* A_log   = (const float*)d_in[11];
    const float* Dp      = (const float*)d_in[12];
    const float* out_w   = (const float*)d_in[13];
    const float* normf_w = (const float*)d_in[14];
    const float* normf_b = (const float*)d_in[15];
    const float* head_w  = (const float*)d_in[16];
    const float* head_b  = (const float*)d_in[17];

    float* ws = (float*)d_ws;
    float* residual     = ws;                          // 2,408,448 f
    float* hidden       = ws + 2408448;                // 2,408,448 f
    float* xz           = ws + 4816896;                // 9,633,792 f
    ushort_t* xcbf      = (ushort_t*)(ws + 14450688);  // 4,816,896 u16
    ushort_t* y_bf      = (ushort_t*)(ws + 16859136);  // 4,816,896 u16
    ushort_t* x_bf      = (ushort_t*)(ws + 14450688);  // 9,633,792 u16 (aliases xcbf+y_bf; dead before layer 0 conv)
    ushort_t* normed_bf = (ushort_t*)(ws + 19267584);  // 2,408,448 u16 (union w/ xdbl)
    float* xdbl         = ws + 19267584;               // 614,656 f (union w/ normed_bf; disjoint lifetime)
    float* pooled       = ws + 20471808;               // 12,288 f
    ushort_t* in_w_bf   = (ushort_t*)(ws + 20484096);  // 3,538,944 u16
    ushort_t* out_w_bf  = (ushort_t*)(ws + 22253568);  // 1,769,472 u16
    ushort_t* xp_w_bf   = (ushort_t*)(ws + 23138304);  // 589,824 u16 (padded 24x64x384)
    ushort_t* patch_w_bf= (ushort_t*)(ws + 23433216);  // 147,456 u16
    // end: 23,506,944 floats = 94.0 MB

    hipMemsetAsync(residual, 0, (size_t)2408448 * sizeof(float), stream);

    // one-time casts
    f2bf4_kernel<<<3456, 256, 0, stream>>>(in_w, in_w_bf, 884736);
    f2bf4_kernel<<<1728, 256, 0, stream>>>(out_w, out_w_bf, 442368);
    f2bf4_kernel<<<144, 256, 0, stream>>>(patch_w, patch_w_bf, 36864);
    f2bf4_kernel<<<9408, 256, 0, stream>>>(x, x_bf, 2408448);
    xp_pad_kernel<<<2304, 256, 0, stream>>>(xp_w, xp_w_bf);

    gemm_patch_mfma<<<dim3(98, 3), 256, 0, stream>>>(x_bf, patch_w_bf, patch_b, hidden);

    for (int d = 0; d < DEPTH; ++d) {
        ln_kernel<true><<<3136, 256, 0, stream>>>(residual, hidden, norm_w + d * DM,
                                                  norm_b + d * DM, normed_bf);
        // in_proj: [12544,192] x [768,192]^T -> xz
        gemm_mfma<192, 2, 2, 12><<<dim3(98, 4), 256, 0, stream>>>(normed_bf,
                in_w_bf + (size_t)d * 768 * 192, xz, 192, 768);
        conv_silu_kernel<<<18816, 256, 0, stream>>>(xz, conv_w + d * DI * 4, conv_b + d * DI, xcbf);
        // x_proj: [12544,384] x [64(pad),384]^T -> xdbl (stride 49, cols 0..47)
        gemm_mfma<64, 4, 1, 3><<<dim3(98, 1), 256, 0, stream>>>(xcbf,
                xp_w_bf + (size_t)d * 64 * 384, xdbl, 384, XDS);
        scan_kernel<<<dim3(64, 96), 256, 0, stream>>>(xdbl, xcbf, xz, dt_w + d * DI * DR, dt_b + d * DI,
                                                      A_log + d * DI * DS, Dp + d * DI, y_bf);
        // out_proj: [12544,384] x [192,384]^T -> hidden
        gemm_mfma<64, 4, 1, 4><<<dim3(98, 3), 256, 0, stream>>>(y_bf,
                out_w_bf + (size_t)d * 192 * 384, hidden, 384, 192);
    }

    ln_kernel<false><<<3136, 256, 0, stream>>>(residual, hidden, normf_w, normf_b, xz);
    pool_kernel<<<64, 192, 0, stream>>>(xz, pooled);
    gemm64<true><<<dim3(1, 16), 256, 0, stream>>>(pooled, head_w, head_b, (float*)d_out, 64, 1000, 192);
}